// Round 9
// baseline (118.661 us; speedup 1.0000x reference)
//
#include <hip/hip_runtime.h>
#include <hip/hip_bf16.h>
#include <math.h>

#define NB 32          // batch
#define TLEN 160000    // samples per batch
#define HOP 600
#define NBINS 256
#define TT 267         // frames: 1 + (160000+1024-1024)/600
#define TTP 268        // padded row stride (even -> aligned float2 stores)
#define NROWS (NB * NBINS)  // 8192
#define LMAX 13

__device__ __forceinline__ unsigned f2key(float f) {
    unsigned b = __float_as_uint(f);
    return (b & 0x80000000u) ? ~b : (b | 0x80000000u);
}
// LDS +1-per-16 padding
__device__ __forceinline__ int P(int i) { return i + (i >> 4); }
__device__ __forceinline__ float2 cmul(float2 a, float2 w) {
    return make_float2(a.x * w.x - a.y * w.y, a.x * w.y + a.y * w.x);
}
__device__ __forceinline__ float2 cadd(float2 a, float2 b) { return make_float2(a.x + b.x, a.y + b.y); }
__device__ __forceinline__ float2 csub(float2 a, float2 b) { return make_float2(a.x - b.x, a.y - b.y); }

// ---------------------------------------------------------------- init: twiddles + window
__global__ void init_kernel(float2* __restrict__ tw, float* __restrict__ wtab) {
    int j = blockIdx.x * blockDim.x + threadIdx.x;
    if (j < 512) {
        double ang = -2.0 * 3.14159265358979323846 * (double)j / 1024.0;
        tw[j] = make_float2((float)cos(ang), (float)sin(ang));
    }
    if (j < 800) {
        float arg = (6.2831855f * (float)j) / 800.0f;
        wtab[j] = 0.5f - 0.5f * cosf(arg);
    }
}

// ---------------------------------------------------------------- STFT power
// ONE 1024-pt complex DIF FFT PER WAVE (two real frames packed re/im).
// Lane j holds elements {j+64k}. Strides 512..64 in-register, strides 32..1
// via shfl_xor. Single barrier (twiddle staging); waves free-run after it.
__global__ __launch_bounds__(256) void stft_power_kernel(
        const float* __restrict__ y, const float2* __restrict__ twg,
        const float* __restrict__ wtab, float* __restrict__ Y) {
    __shared__ float2 twl[544];
    __shared__ float2 zbin[4][1088];    // per-wave P-padded bin-order spectrum

    const int tid = threadIdx.x;
    const int lane = tid & 63;
    const int wv = tid >> 6;
    const int b = blockIdx.y;

    for (int j = tid; j < 512; j += 256) twl[P(j)] = twg[j];
    __syncthreads();                    // the only barrier

    const int wave_id = blockIdx.x * 4 + wv;
    const int f0 = 2 * wave_id;
    if (f0 >= TT) return;               // tail waves exit (after the barrier)
    const bool hasB = (f0 + 1 < TT);

    const float* yb = y + (size_t)b * TLEN;
    const int base = f0 * HOP - 512;    // reflect pad K/2 = 512

    // ---- gather + window (coalesced: fixed k -> consecutive lanes)
    float2 x[16];
    #pragma unroll
    for (int k = 0; k < 16; ++k) {
        const int n = lane + 64 * k;
        float v0 = 0.f, v1 = 0.f;
        if (n >= 112 && n < 912) {      // centered 800-tap hann
            float w = wtab[n - 112];
            int p0 = base + n;
            int q0 = p0 < 0 ? -p0 : p0; // left reflect (f0==0 only); right never
            v0 = yb[q0] * w;
            if (hasB) v1 = yb[p0 + HOP] * w;   // p0+HOP >= 200, in bounds
        }
        x[k] = make_float2(v0, v1);
    }

    // ---- in-register DIF stages H=512,256,128,64 (same twiddles/ops as before)
    #pragma unroll
    for (int k = 0; k < 8; ++k) {           // H=512: e = lane+64k
        float2 a = x[k], bb = x[k + 8];
        x[k] = cadd(a, bb);
        x[k + 8] = cmul(csub(a, bb), twl[P(lane + 64 * k)]);
    }
    #pragma unroll
    for (int h = 0; h < 16; h += 8)         // H=256: e = 2*lane+128k
        #pragma unroll
        for (int k = 0; k < 4; ++k) {
            float2 a = x[h + k], bb = x[h + k + 4];
            x[h + k] = cadd(a, bb);
            x[h + k + 4] = cmul(csub(a, bb), twl[P(2 * lane + 128 * k)]);
        }
    #pragma unroll
    for (int h = 0; h < 16; h += 4)         // H=128: e = 4*lane+256k
        #pragma unroll
        for (int k = 0; k < 2; ++k) {
            float2 a = x[h + k], bb = x[h + k + 2];
            x[h + k] = cadd(a, bb);
            x[h + k + 2] = cmul(csub(a, bb), twl[P(4 * lane + 256 * k)]);
        }
    {
        const float2 wD = twl[P(8 * lane)]; // H=64: e = 8*lane
        #pragma unroll
        for (int h = 0; h < 16; h += 2) {
            float2 a = x[h], bb = x[h + 1];
            x[h] = cadd(a, bb);
            x[h + 1] = cmul(csub(a, bb), wD);
        }
    }

    // ---- cross-lane DIF stages H=32,16,8,4 via shfl_xor (e = (512/H)*(lane%H))
    #pragma unroll
    for (int st = 0; st < 4; ++st) {
        const int dlt = 32 >> st;                       // 32,16,8,4
        const float2 wD = twl[P((16 << st) * (lane & (dlt - 1)))];
        const bool upper = (lane & dlt) != 0;
        #pragma unroll
        for (int k = 0; k < 16; ++k) {
            float2 p = make_float2(__shfl_xor(x[k].x, dlt), __shfl_xor(x[k].y, dlt));
            x[k] = upper ? cmul(csub(p, x[k]), wD) : cadd(x[k], p);
        }
    }
    {   // H=2: pairs (lane, lane^2); upper multiplies by W^{256*(lane&1)} (1 or -i)
        const bool odd = (lane & 1) != 0;
        const bool upper = (lane & 2) != 0;
        #pragma unroll
        for (int k = 0; k < 16; ++k) {
            float2 p = make_float2(__shfl_xor(x[k].x, 2), __shfl_xor(x[k].y, 2));
            if (!upper) x[k] = cadd(x[k], p);
            else {
                float2 d = csub(p, x[k]);
                x[k] = odd ? make_float2(d.y, -d.x) : d;
            }
        }
    }
    {   // H=1: plain butterfly (lane, lane^1)
        const bool upper = (lane & 1) != 0;
        #pragma unroll
        for (int k = 0; k < 16; ++k) {
            float2 p = make_float2(__shfl_xor(x[k].x, 1), __shfl_xor(x[k].y, 1));
            x[k] = upper ? csub(p, x[k]) : cadd(x[k], p);
        }
    }

    // ---- scatter to bin order: out[lane+64k] = Z[16*brev6(lane)+brev4(k)]
    float2* zb = zbin[wv];
    const int mrev = (int)(__brev((unsigned)lane) >> 26);   // brev6(lane)
    #pragma unroll
    for (int k = 0; k < 16; ++k) {
        const int slot = 16 * mrev + (int)(__brev((unsigned)k) >> 28);
        zb[P(slot)] = x[k];
    }
    // wave-private LDS: compiler inserts lgkmcnt waits for the aliasing reads

    // ---- conjugate unpack of two real spectra; bins 0..255
    #pragma unroll
    for (int c = 0; c < 4; ++c) {
        const int bin = lane + 64 * c;
        float2 zk = zb[P(bin)];
        float2 zn = zb[P((1024 - bin) & 1023)];
        float x0r = 0.5f * (zk.x + zn.x), x0i = 0.5f * (zk.y - zn.y);
        float x1r = 0.5f * (zk.y + zn.y), x1i = 0.5f * (zn.x - zk.x);
        float* pr = Y + ((size_t)b * NBINS + bin) * TTP + f0;
        if (hasB) *(float2*)pr = make_float2(x0r * x0r + x0i * x0i,
                                             x1r * x1r + x1i * x1i);
        else      *pr = x0r * x0r + x0i * x0i;
    }
}

// ---------------------------------------------------------------- per-subband
// ONE ROW PER WAVE (2048 blocks x 4 waves). dec flags in ballot registers,
// wave-local compaction, private per-row output region, NO atomics.
__global__ __launch_bounds__(256) void subband_kernel(
        const float* __restrict__ Y, unsigned* __restrict__ compact,
        int* __restrict__ rowcnt) {
    __shared__ float ys[4][272];

    const int tid = threadIdx.x;
    const int lane = tid & 63;
    const int wave = tid >> 6;
    const int row = blockIdx.x * 4 + wave;
    const float* src = Y + (size_t)row * TTP;

    float v[5];
    #pragma unroll
    for (int c = 0; c < 5; ++c) {
        int t = c * 64 + lane;
        v[c] = (t < TT) ? src[t] : 0.0f;
        if (t < TT) ys[wave][t] = v[c];
    }
    __syncthreads();                 // the only barrier

    const float* yy = ys[wave];

    unsigned long long m[5];
    #pragma unroll
    for (int c = 0; c < 5; ++c) {
        int t = c * 64 + lane;
        bool d = (t < TT - 1) && (yy[t + 1] < v[c]);
        m[c] = __ballot(d);
    }

    auto runl = [&](int c, int l) -> int {
        unsigned long long lo = m[c] >> l;
        if (l && c < 4) lo |= m[c + 1] << (64 - l);
        unsigned win = (unsigned)lo & 0xFFFu;
        return (win == 0xFFFu) ? 12 : (__ffs((int)~win) - 1);
    };

    int rl[5];
    int mx = 0;
    #pragma unroll
    for (int c = 0; c < 5; ++c) { rl[c] = runl(c, lane); mx = max(mx, rl[c]); }
    #pragma unroll
    for (int o = 32; o; o >>= 1) mx = max(mx, __shfl_xor(mx, o));
    const int maxrun = mx;           // capped at 12, uniform across wave

    if (maxrun < 2) {                // has_any == false
        if (lane == 0) rowcnt[row] = 0;
        return;
    }
    const int L = maxrun + 1;        // == min(13, true_maxrun+1)

    float sumx = 0.0f;
    #pragma unroll
    for (int j = 0; j < LMAX; ++j) if (j < L) sumx += (float)j;
    const float xm = sumx / (float)L;
    float den = 0.0f;
    #pragma unroll
    for (int j = 0; j < LMAX; ++j) if (j < L) { float xc = (float)j - xm; den += xc * xc; }

    unsigned keys[5];
    unsigned long long vm[5];
    #pragma unroll
    for (int c = 0; c < 5; ++c) {
        const int t = c * 64 + lane;
        bool sel = false;
        unsigned key = 0u;
        if (rl[c] >= L - 1) {        // start_mask (t+L<=T implied by run len)
            float edc[LMAX];
            float s = 0.0f;
            #pragma unroll
            for (int j = LMAX - 1; j >= 0; --j) {
                if (j < L) s += yy[t + j];
                edc[j] = s;
            }
            float db0 = 10.0f * log10f(fmaxf(edc[0], 1e-10f));
            float scl[LMAX];
            float s1 = 0.0f;
            float last = 0.0f;
            #pragma unroll
            for (int j = 0; j < LMAX; ++j) {
                if (j < L) {
                    float db = 10.0f * log10f(fmaxf(edc[j], 1e-10f));
                    float sc = db - db0;
                    scl[j] = sc;
                    s1 += sc;
                    if (j == L - 1) last = sc;
                }
            }
            if (last < -10.0f) {     // selected
                const float ym = s1 / (float)L;
                float num = 0.0f;
                #pragma unroll
                for (int j = 0; j < LMAX; ++j)
                    if (j < L) num += ((float)j - xm) * (scl[j] - ym);
                const float slope = num / den;
                float rt60 = (-60.0f / slope) * 0.0375f;   // * HOP/FS
                sel = true;
                key = f2key(rt60);
            }
        }
        vm[c] = __ballot(sel);       // uniform point
        keys[c] = key;
    }

    unsigned* dst = compact + (size_t)row * TTP;
    const unsigned long long below = (1ull << lane) - 1ull;
    int base = 0;
    #pragma unroll
    for (int c = 0; c < 5; ++c) {
        if (vm[c] & (1ull << lane))
            dst[base + (int)__popcll(vm[c] & below)] = keys[c];
        base += (int)__popcll(vm[c]);
    }
    if (lane == 0) rowcnt[row] = base;
}

// ---------------------------------------------------------------- median
// one block per batch: exact k-th smallest via 3-pass (14+14+4 bit) LDS radix
// select. Conflict-free chunk sums (rotated index), shfl-based parallel rank
// selection (no serial tid0 scans).
__global__ __launch_bounds__(256) void median_kernel(
        const unsigned* __restrict__ compact, const int* __restrict__ rowcnt,
        const float* __restrict__ coeffs, float* __restrict__ out) {
    __shared__ unsigned hist[16384];
    __shared__ unsigned wsum[4];
    __shared__ int sh_sel;
    __shared__ unsigned sh_kkc;
    __shared__ unsigned sh_kk, sh_prefix, sh_pmask;
    __shared__ int sh_n;

    const int b = blockIdx.x;
    const int tid = threadIdx.x;
    const int lane = tid & 63;
    const int wave = tid >> 6;
    const int myrow = b * NBINS + tid;
    const int myc = rowcnt[myrow];
    const unsigned* mykeys = compact + (size_t)myrow * TTP;

    {
        unsigned x = (unsigned)myc;
        #pragma unroll
        for (int o = 1; o < 64; o <<= 1) { unsigned t = __shfl_up(x, o); if (lane >= o) x += t; }
        if (lane == 63) wsum[wave] = x;
        __syncthreads();
        if (tid == 0) {
            int n = (int)(wsum[0] + wsum[1] + wsum[2] + wsum[3]);
            sh_n = n;
            sh_kk = (n > 0) ? (unsigned)((n - 1) / 2) : 0u;
            sh_prefix = 0u; sh_pmask = 0u;
        }
        __syncthreads();
    }
    const int n = sh_n;
    if (n == 0) {
        if (tid == 0) out[b] = 0.5f;     // DEFAULT_RT60 (> 0.01 clamp)
        return;
    }

    const int shifts[3] = {18, 4, 0};
    for (int p = 0; p < 3; ++p) {
        const int shift = shifts[p];
        const bool big = (p < 2);

        if (big) {
            uint4* h4 = (uint4*)hist;
            for (int i = tid; i < 4096; i += 256) h4[i] = make_uint4(0u, 0u, 0u, 0u);
        } else if (tid < 16) hist[tid] = 0u;
        __syncthreads();

        const unsigned pfx = sh_prefix, pm = sh_pmask;
        const unsigned bmask = big ? 16383u : 15u;
        for (int i = 0; i < myc; ++i) {
            unsigned k = mykeys[i];
            if ((k & pm) == pfx) atomicAdd(&hist[(k >> shift) & bmask], 1u);
        }
        __syncthreads();

        const unsigned kk = sh_kk;
        if (big) {
            unsigned s = 0;
            const int base = tid * 64;
            #pragma unroll 8
            for (int ii = 0; ii < 64; ++ii) s += hist[base + ((ii + tid) & 63)];
            unsigned x = s;
            #pragma unroll
            for (int o = 1; o < 64; o <<= 1) { unsigned t = __shfl_up(x, o); if (lane >= o) x += t; }
            if (lane == 63) wsum[wave] = x;
            __syncthreads();
            unsigned woff = 0;
            for (int w = 0; w < wave; ++w) woff += wsum[w];
            const unsigned incl = x + woff, excl = incl - s;
            if (kk >= excl && kk < incl) { sh_sel = tid; sh_kkc = kk - excl; }
            __syncthreads();
            const int sel = sh_sel;
            const unsigned kkc = sh_kkc;
            if (wave == 0) {
                unsigned h = hist[sel * 64 + lane];
                unsigned xx = h;
                #pragma unroll
                for (int o = 1; o < 64; o <<= 1) { unsigned t = __shfl_up(xx, o); if (lane >= o) xx += t; }
                unsigned ex = xx - h;
                if (kkc >= ex && kkc < xx) {
                    sh_prefix = pfx | ((unsigned)(sel * 64 + lane) << shift);
                    sh_pmask  = pm | (16383u << shift);
                    sh_kk = kkc - ex;
                }
            }
            __syncthreads();
        } else {
            if (wave == 0) {
                unsigned h = (lane < 16) ? hist[lane] : 0u;
                unsigned xx = h;
                #pragma unroll
                for (int o = 1; o < 64; o <<= 1) { unsigned t = __shfl_up(xx, o); if (lane >= o) xx += t; }
                unsigned ex = xx - h;
                if (lane < 16 && kk >= ex && kk < xx)
                    sh_prefix = pfx | (unsigned)lane;   // shift == 0
            }
            __syncthreads();
        }
    }

    if (tid == 0) {
        unsigned kx = sh_prefix;
        unsigned fb = (kx & 0x80000000u) ? (kx & 0x7FFFFFFFu) : ~kx;
        float med = __uint_as_float(fb);
        out[b] = fmaxf(coeffs[0] + coeffs[1] * med, 0.01f);
    }
}

// ----------------------------------------------------------------
extern "C" void kernel_launch(void* const* d_in, const int* in_sizes, int n_in,
                              void* d_out, int out_size, void* d_ws, size_t ws_size,
                              hipStream_t stream) {
    const float* y = (const float*)d_in[0];
    const float* coeffs = (const float*)d_in[1];
    float* out = (float*)d_out;

    // ws layout:
    //   [0]        Y       : NROWS*TTP floats (stride-268 rows)
    //   [YB]       compact : NROWS*TTP uints (per-row private regions)
    //   [2*YB]     rowcnt  : NROWS ints (fully overwritten per call)
    //   [..]       tw      : 512 float2 ; wtab : 800 floats
    const size_t YB = (size_t)NROWS * TTP * sizeof(float);
    char* base = (char*)d_ws;
    float* Y = (float*)base;
    unsigned* compact = (unsigned*)(base + YB);
    int* rowcnt = (int*)(base + 2 * YB);
    float2* tw = (float2*)(base + 2 * YB + (size_t)NROWS * sizeof(int));
    float* wtab = (float*)((char*)tw + 512 * sizeof(float2));

    init_kernel<<<4, 256, 0, stream>>>(tw, wtab);
    // 134 frame-pair waves per batch -> 34 blocks of 4 waves
    stft_power_kernel<<<dim3(34, NB), 256, 0, stream>>>(y, tw, wtab, Y);
    subband_kernel<<<NROWS / 4, 256, 0, stream>>>(Y, compact, rowcnt);
    median_kernel<<<NB, 256, 0, stream>>>(compact, rowcnt, coeffs, out);
}

// Round 10
// 106.698 us; speedup vs baseline: 1.1121x; 1.1121x over previous
//
#include <hip/hip_runtime.h>
#include <hip/hip_bf16.h>
#include <math.h>

#define NB 32          // batch
#define TLEN 160000    // samples per batch
#define HOP 600
#define NBINS 256
#define TT 267         // frames: 1 + (160000+1024-1024)/600
#define TTP 268        // padded row stride (16B-aligned rows: 1072 B)
#define NROWS (NB * NBINS)  // 8192
#define LMAX 13

__device__ __forceinline__ unsigned f2key(float f) {
    unsigned b = __float_as_uint(f);
    return (b & 0x80000000u) ? ~b : (b | 0x80000000u);
}
// twiddle LDS padding
__device__ __forceinline__ int P(int i) { return i + (i >> 4); }
// data LDS XOR swizzle: conflict-free for stride-64 sets, stride-4 sets,
// and quad-contiguous b128 access
__device__ __forceinline__ int Q(int i) { return i ^ ((i >> 4) & 0x3C); }
__device__ __forceinline__ float2 cmul(float2 a, float2 w) {
    return make_float2(a.x * w.x - a.y * w.y, a.x * w.y + a.y * w.x);
}
__device__ __forceinline__ float2 cadd(float2 a, float2 b) { return make_float2(a.x + b.x, a.y + b.y); }
__device__ __forceinline__ float2 csub(float2 a, float2 b) { return make_float2(a.x - b.x, a.y - b.y); }

// ---------------------------------------------------------------- init: twiddles + window
__global__ void init_kernel(float2* __restrict__ tw, float* __restrict__ wtab) {
    int j = blockIdx.x * blockDim.x + threadIdx.x;
    if (j < 512) {
        double ang = -2.0 * 3.14159265358979323846 * (double)j / 1024.0;
        tw[j] = make_float2((float)cos(ang), (float)sin(ang));
    }
    if (j < 800) {
        float arg = (6.2831855f * (float)j) / 800.0f;
        wtab[j] = 0.5f - 0.5f * cosf(arg);
    }
}

// ---------------------------------------------------------------- STFT power
// one block per (8 frames, batch) = 4 complex 1024-pt DIF FFTs (each packs two
// real frames). Radix-16/16/4 decomposition: 3 LDS round-trips, 4 barriers.
// Y written as 2x float4 per bin (8 contiguous frame powers) -> half the
// scattered store instructions vs per-frame float2.
__global__ __launch_bounds__(256) void stft_power_kernel(
        const float* __restrict__ y, const float2* __restrict__ twg,
        const float* __restrict__ wtab, float* __restrict__ Y) {
    __shared__ float2 zz[4][1024];
    __shared__ float2 twl[544];

    const int g = blockIdx.x;
    const int b = blockIdx.y;
    const int tid = threadIdx.x;
    const int f0 = 8 * g;

    for (int j = tid; j < 512; j += 256) twl[P(j)] = twg[j];

    // ---- stage in: window + pack two real frames per FFT (coalesced float4)
    const float* yb = y + (size_t)b * TLEN;
    #pragma unroll
    for (int a = 0; a < 4; ++a) {
        const int fa = f0 + 2 * a;
        if (fa >= TT) break;
        const bool hasB = (fa + 1 < TT);
        const int base = fa * HOP - 512;        // reflect pad K/2 = 512
        const int i = 4 * tid;
        float2 q4[4];
        if (base >= 0 && hasB) {                // fast path: no reflection possible
            if (i >= 112 && i < 912) {          // centered 800-tap hann
                float4 w4 = *(const float4*)(wtab + (i - 112));
                float4 a0 = *(const float4*)(yb + base + i);
                float4 a1 = *(const float4*)(yb + base + HOP + i);
                q4[0] = make_float2(a0.x * w4.x, a1.x * w4.x);
                q4[1] = make_float2(a0.y * w4.y, a1.y * w4.y);
                q4[2] = make_float2(a0.z * w4.z, a1.z * w4.z);
                q4[3] = make_float2(a0.w * w4.w, a1.w * w4.w);
            } else {
                q4[0] = q4[1] = q4[2] = q4[3] = make_float2(0.f, 0.f);
            }
        } else {                                // fa==0 (left reflect) or fa==266
            #pragma unroll
            for (int m = 0; m < 4; ++m) {
                const int ii = i + m;
                float v0 = 0.f, v1 = 0.f;
                if (ii >= 112 && ii < 912) {
                    float w = wtab[ii - 112];
                    int p0 = base + ii;
                    int q0 = p0 < 0 ? -p0 : p0; // right edge never reflects
                    v0 = yb[q0] * w;
                    if (hasB) v1 = yb[p0 + HOP] * w;
                }
                q4[m] = make_float2(v0, v1);
            }
        }
        float4* dst = (float4*)&zz[a][Q(i)];    // Q preserves quad contiguity
        dst[0] = make_float4(q4[0].x, q4[0].y, q4[1].x, q4[1].y);
        dst[1] = make_float4(q4[2].x, q4[2].y, q4[3].x, q4[3].y);
    }
    __syncthreads();

    // ---- round 1: DIF layers H=512,256,128,64 on {j + 64k} in registers
    {
        const int a = tid >> 6, j = tid & 63;
        float2 x[16];
        #pragma unroll
        for (int k = 0; k < 16; ++k) x[k] = zz[a][Q(j + 64 * k)];
        #pragma unroll
        for (int k = 0; k < 8; ++k) {           // H=512
            float2 s = csub(x[k], x[k + 8]);
            x[k] = cadd(x[k], x[k + 8]);
            x[k + 8] = cmul(s, twl[P(j + 64 * k)]);
        }
        #pragma unroll
        for (int h = 0; h < 16; h += 8)         // H=256
            #pragma unroll
            for (int k = 0; k < 4; ++k) {
                float2 s = csub(x[h + k], x[h + k + 4]);
                x[h + k] = cadd(x[h + k], x[h + k + 4]);
                x[h + k + 4] = cmul(s, twl[P(2 * j + 128 * k)]);
            }
        #pragma unroll
        for (int h = 0; h < 16; h += 4)         // H=128
            #pragma unroll
            for (int k = 0; k < 2; ++k) {
                float2 s = csub(x[h + k], x[h + k + 2]);
                x[h + k] = cadd(x[h + k], x[h + k + 2]);
                x[h + k + 2] = cmul(s, twl[P(4 * j + 256 * k)]);
            }
        {
            const float2 wD = twl[P(8 * j)];    // H=64
            #pragma unroll
            for (int h = 0; h < 16; h += 2) {
                float2 s = csub(x[h], x[h + 1]);
                x[h] = cadd(x[h], x[h + 1]);
                x[h + 1] = cmul(s, wD);
            }
        }
        #pragma unroll
        for (int k = 0; k < 16; ++k) zz[a][Q(j + 64 * k)] = x[k];
    }
    __syncthreads();

    // ---- round 2: DIF layers H=32,16,8,4 on {64g + j2 + 4k} in registers
    {
        const int a = tid >> 6, l = tid & 63;
        const int gg = l >> 2, j2 = l & 3;
        const int b0 = 64 * gg + j2;
        float2 x[16];
        #pragma unroll
        for (int k = 0; k < 16; ++k) x[k] = zz[a][Q(b0 + 4 * k)];
        #pragma unroll
        for (int k = 0; k < 8; ++k) {           // H=32
            float2 s = csub(x[k], x[k + 8]);
            x[k] = cadd(x[k], x[k + 8]);
            x[k + 8] = cmul(s, twl[P(16 * j2 + 64 * k)]);
        }
        #pragma unroll
        for (int h = 0; h < 16; h += 8)         // H=16
            #pragma unroll
            for (int k = 0; k < 4; ++k) {
                float2 s = csub(x[h + k], x[h + k + 4]);
                x[h + k] = cadd(x[h + k], x[h + k + 4]);
                x[h + k + 4] = cmul(s, twl[P(32 * j2 + 128 * k)]);
            }
        #pragma unroll
        for (int h = 0; h < 16; h += 4)         // H=8
            #pragma unroll
            for (int k = 0; k < 2; ++k) {
                float2 s = csub(x[h + k], x[h + k + 2]);
                x[h + k] = cadd(x[h + k], x[h + k + 2]);
                x[h + k + 2] = cmul(s, twl[P(64 * (j2 + 4 * k))]);
            }
        {
            const float2 wD = twl[P(128 * j2)]; // H=4
            #pragma unroll
            for (int h = 0; h < 16; h += 2) {
                float2 s = csub(x[h], x[h + 1]);
                x[h] = cadd(x[h], x[h + 1]);
                x[h + 1] = cmul(s, wD);
            }
        }
        #pragma unroll
        for (int k = 0; k < 16; ++k) zz[a][Q(b0 + 4 * k)] = x[k];
    }
    __syncthreads();

    // ---- round 3: twiddle-free radix-4 on quads (b128 via Q contiguity)
    #pragma unroll
    for (int a = 0; a < 4; ++a) {
        float4* pp = (float4*)&zz[a][Q(4 * tid)];
        float4 r0 = pp[0], r1 = pp[1];
        float2 x0 = make_float2(r0.x, r0.y), x1 = make_float2(r0.z, r0.w);
        float2 x2 = make_float2(r1.x, r1.y), x3 = make_float2(r1.z, r1.w);
        float2 e0 = cadd(x0, x2);
        float2 e1 = cadd(x1, x3);
        float2 d0 = csub(x0, x2);
        float2 d1 = csub(x1, x3);
        float2 d1m = make_float2(d1.y, -d1.x);  // * W^256 = -i
        pp[0] = make_float4(e0.x + e1.x, e0.y + e1.y, e0.x - e1.x, e0.y - e1.y);
        pp[1] = make_float4(d0.x + d1m.x, d0.y + d1m.y, d0.x - d1m.x, d0.y - d1m.y);
    }
    __syncthreads();

    // ---- unpack two real spectra per FFT; Z[k] sits at brev10(k)
    const int k = tid;
    const int nk = (1024 - k) & 1023;
    const int rk = (int)(__brev((unsigned)k) >> 22);
    const int rn = (int)(__brev((unsigned)nk) >> 22);
    float* yrow = Y + ((size_t)b * NBINS + k) * TTP;
    if (g < 33) {                       // all 8 frames valid: 2x float4 stores
        float p[8];
        #pragma unroll
        for (int a = 0; a < 4; ++a) {
            float2 zk = zz[a][Q(rk)], zn = zz[a][Q(rn)];
            float x0r = 0.5f * (zk.x + zn.x), x0i = 0.5f * (zk.y - zn.y);
            float x1r = 0.5f * (zk.y + zn.y), x1i = 0.5f * (zn.x - zk.x);
            p[2 * a]     = x0r * x0r + x0i * x0i;
            p[2 * a + 1] = x1r * x1r + x1i * x1i;
        }
        *(float4*)(yrow + f0)     = make_float4(p[0], p[1], p[2], p[3]);
        *(float4*)(yrow + f0 + 4) = make_float4(p[4], p[5], p[6], p[7]);
    } else {                            // tail block (frames 264..266)
        #pragma unroll
        for (int a = 0; a < 4; ++a) {
            const int fa = f0 + 2 * a;
            if (fa >= TT) break;
            float2 zk = zz[a][Q(rk)], zn = zz[a][Q(rn)];
            float x0r = 0.5f * (zk.x + zn.x), x0i = 0.5f * (zk.y - zn.y);
            float x1r = 0.5f * (zk.y + zn.y), x1i = 0.5f * (zn.x - zk.x);
            if (fa + 1 < TT)
                *(float2*)(yrow + fa) = make_float2(x0r * x0r + x0i * x0i,
                                                    x1r * x1r + x1i * x1i);
            else
                yrow[fa] = x0r * x0r + x0i * x0i;
        }
    }
}

// ---------------------------------------------------------------- per-subband
// ONE ROW PER WAVE (2048 blocks x 4 waves). dec flags in ballot registers,
// wave-local compaction, private per-row output region, NO atomics.
__global__ __launch_bounds__(256) void subband_kernel(
        const float* __restrict__ Y, unsigned* __restrict__ compact,
        int* __restrict__ rowcnt) {
    __shared__ float ys[4][272];

    const int tid = threadIdx.x;
    const int lane = tid & 63;
    const int wave = tid >> 6;
    const int row = blockIdx.x * 4 + wave;
    const float* src = Y + (size_t)row * TTP;

    float v[5];
    #pragma unroll
    for (int c = 0; c < 5; ++c) {
        int t = c * 64 + lane;
        v[c] = (t < TT) ? src[t] : 0.0f;
        if (t < TT) ys[wave][t] = v[c];
    }
    __syncthreads();                 // the only barrier

    const float* yy = ys[wave];

    unsigned long long m[5];
    #pragma unroll
    for (int c = 0; c < 5; ++c) {
        int t = c * 64 + lane;
        bool d = (t < TT - 1) && (yy[t + 1] < v[c]);
        m[c] = __ballot(d);
    }

    auto runl = [&](int c, int l) -> int {
        unsigned long long lo = m[c] >> l;
        if (l && c < 4) lo |= m[c + 1] << (64 - l);
        unsigned win = (unsigned)lo & 0xFFFu;
        return (win == 0xFFFu) ? 12 : (__ffs((int)~win) - 1);
    };

    int rl[5];
    int mx = 0;
    #pragma unroll
    for (int c = 0; c < 5; ++c) { rl[c] = runl(c, lane); mx = max(mx, rl[c]); }
    #pragma unroll
    for (int o = 32; o; o >>= 1) mx = max(mx, __shfl_xor(mx, o));
    const int maxrun = mx;           // capped at 12, uniform across wave

    if (maxrun < 2) {                // has_any == false
        if (lane == 0) rowcnt[row] = 0;
        return;
    }
    const int L = maxrun + 1;        // == min(13, true_maxrun+1)

    float sumx = 0.0f;
    #pragma unroll
    for (int j = 0; j < LMAX; ++j) if (j < L) sumx += (float)j;
    const float xm = sumx / (float)L;
    float den = 0.0f;
    #pragma unroll
    for (int j = 0; j < LMAX; ++j) if (j < L) { float xc = (float)j - xm; den += xc * xc; }

    unsigned keys[5];
    unsigned long long vm[5];
    #pragma unroll
    for (int c = 0; c < 5; ++c) {
        const int t = c * 64 + lane;
        bool sel = false;
        unsigned key = 0u;
        if (rl[c] >= L - 1) {        // start_mask (t+L<=T implied by run len)
            float edc[LMAX];
            float s = 0.0f;
            #pragma unroll
            for (int j = LMAX - 1; j >= 0; --j) {
                if (j < L) s += yy[t + j];
                edc[j] = s;
            }
            float db0 = 10.0f * log10f(fmaxf(edc[0], 1e-10f));
            float scl[LMAX];
            float s1 = 0.0f;
            float last = 0.0f;
            #pragma unroll
            for (int j = 0; j < LMAX; ++j) {
                if (j < L) {
                    float db = 10.0f * log10f(fmaxf(edc[j], 1e-10f));
                    float sc = db - db0;
                    scl[j] = sc;
                    s1 += sc;
                    if (j == L - 1) last = sc;
                }
            }
            if (last < -10.0f) {     // selected
                const float ym = s1 / (float)L;
                float num = 0.0f;
                #pragma unroll
                for (int j = 0; j < LMAX; ++j)
                    if (j < L) num += ((float)j - xm) * (scl[j] - ym);
                const float slope = num / den;
                float rt60 = (-60.0f / slope) * 0.0375f;   // * HOP/FS
                sel = true;
                key = f2key(rt60);
            }
        }
        vm[c] = __ballot(sel);       // uniform point
        keys[c] = key;
    }

    unsigned* dst = compact + (size_t)row * TTP;
    const unsigned long long below = (1ull << lane) - 1ull;
    int base = 0;
    #pragma unroll
    for (int c = 0; c < 5; ++c) {
        if (vm[c] & (1ull << lane))
            dst[base + (int)__popcll(vm[c] & below)] = keys[c];
        base += (int)__popcll(vm[c]);
    }
    if (lane == 0) rowcnt[row] = base;
}

// ---------------------------------------------------------------- median
// one block per batch: exact k-th smallest via 3-pass (14+14+4 bit) LDS radix
// select. Conflict-free chunk sums (rotated index), shfl-based parallel rank
// selection (no serial tid0 scans).
__global__ __launch_bounds__(256) void median_kernel(
        const unsigned* __restrict__ compact, const int* __restrict__ rowcnt,
        const float* __restrict__ coeffs, float* __restrict__ out) {
    __shared__ unsigned hist[16384];
    __shared__ unsigned wsum[4];
    __shared__ int sh_sel;
    __shared__ unsigned sh_kkc;
    __shared__ unsigned sh_kk, sh_prefix, sh_pmask;
    __shared__ int sh_n;

    const int b = blockIdx.x;
    const int tid = threadIdx.x;
    const int lane = tid & 63;
    const int wave = tid >> 6;
    const int myrow = b * NBINS + tid;
    const int myc = rowcnt[myrow];
    const unsigned* mykeys = compact + (size_t)myrow * TTP;

    {
        unsigned x = (unsigned)myc;
        #pragma unroll
        for (int o = 1; o < 64; o <<= 1) { unsigned t = __shfl_up(x, o); if (lane >= o) x += t; }
        if (lane == 63) wsum[wave] = x;
        __syncthreads();
        if (tid == 0) {
            int n = (int)(wsum[0] + wsum[1] + wsum[2] + wsum[3]);
            sh_n = n;
            sh_kk = (n > 0) ? (unsigned)((n - 1) / 2) : 0u;
            sh_prefix = 0u; sh_pmask = 0u;
        }
        __syncthreads();
    }
    const int n = sh_n;
    if (n == 0) {
        if (tid == 0) out[b] = 0.5f;     // DEFAULT_RT60 (> 0.01 clamp)
        return;
    }

    const int shifts[3] = {18, 4, 0};
    for (int p = 0; p < 3; ++p) {
        const int shift = shifts[p];
        const bool big = (p < 2);

        if (big) {
            uint4* h4 = (uint4*)hist;
            for (int i = tid; i < 4096; i += 256) h4[i] = make_uint4(0u, 0u, 0u, 0u);
        } else if (tid < 16) hist[tid] = 0u;
        __syncthreads();

        const unsigned pfx = sh_prefix, pm = sh_pmask;
        const unsigned bmask = big ? 16383u : 15u;
        for (int i = 0; i < myc; ++i) {
            unsigned k = mykeys[i];
            if ((k & pm) == pfx) atomicAdd(&hist[(k >> shift) & bmask], 1u);
        }
        __syncthreads();

        const unsigned kk = sh_kk;
        if (big) {
            unsigned s = 0;
            const int base = tid * 64;
            #pragma unroll 8
            for (int ii = 0; ii < 64; ++ii) s += hist[base + ((ii + tid) & 63)];
            unsigned x = s;
            #pragma unroll
            for (int o = 1; o < 64; o <<= 1) { unsigned t = __shfl_up(x, o); if (lane >= o) x += t; }
            if (lane == 63) wsum[wave] = x;
            __syncthreads();
            unsigned woff = 0;
            for (int w = 0; w < wave; ++w) woff += wsum[w];
            const unsigned incl = x + woff, excl = incl - s;
            if (kk >= excl && kk < incl) { sh_sel = tid; sh_kkc = kk - excl; }
            __syncthreads();
            const int sel = sh_sel;
            const unsigned kkc = sh_kkc;
            if (wave == 0) {
                unsigned h = hist[sel * 64 + lane];
                unsigned xx = h;
                #pragma unroll
                for (int o = 1; o < 64; o <<= 1) { unsigned t = __shfl_up(xx, o); if (lane >= o) xx += t; }
                unsigned ex = xx - h;
                if (kkc >= ex && kkc < xx) {
                    sh_prefix = pfx | ((unsigned)(sel * 64 + lane) << shift);
                    sh_pmask  = pm | (16383u << shift);
                    sh_kk = kkc - ex;
                }
            }
            __syncthreads();
        } else {
            if (wave == 0) {
                unsigned h = (lane < 16) ? hist[lane] : 0u;
                unsigned xx = h;
                #pragma unroll
                for (int o = 1; o < 64; o <<= 1) { unsigned t = __shfl_up(xx, o); if (lane >= o) xx += t; }
                unsigned ex = xx - h;
                if (lane < 16 && kk >= ex && kk < xx)
                    sh_prefix = pfx | (unsigned)lane;   // shift == 0
            }
            __syncthreads();
        }
    }

    if (tid == 0) {
        unsigned kx = sh_prefix;
        unsigned fb = (kx & 0x80000000u) ? (kx & 0x7FFFFFFFu) : ~kx;
        float med = __uint_as_float(fb);
        out[b] = fmaxf(coeffs[0] + coeffs[1] * med, 0.01f);
    }
}

// ----------------------------------------------------------------
extern "C" void kernel_launch(void* const* d_in, const int* in_sizes, int n_in,
                              void* d_out, int out_size, void* d_ws, size_t ws_size,
                              hipStream_t stream) {
    const float* y = (const float*)d_in[0];
    const float* coeffs = (const float*)d_in[1];
    float* out = (float*)d_out;

    // ws layout:
    //   [0]        Y       : NROWS*TTP floats (stride-268 rows)
    //   [YB]       compact : NROWS*TTP uints (per-row private regions)
    //   [2*YB]     rowcnt  : NROWS ints (fully overwritten per call)
    //   [..]       tw      : 512 float2 ; wtab : 800 floats
    const size_t YB = (size_t)NROWS * TTP * sizeof(float);
    char* base = (char*)d_ws;
    float* Y = (float*)base;
    unsigned* compact = (unsigned*)(base + YB);
    int* rowcnt = (int*)(base + 2 * YB);
    float2* tw = (float2*)(base + 2 * YB + (size_t)NROWS * sizeof(int));
    float* wtab = (float*)((char*)tw + 512 * sizeof(float2));

    init_kernel<<<4, 256, 0, stream>>>(tw, wtab);
    stft_power_kernel<<<dim3((TT + 7) / 8, NB), 256, 0, stream>>>(y, tw, wtab, Y);
    subband_kernel<<<NROWS / 4, 256, 0, stream>>>(Y, compact, rowcnt);
    median_kernel<<<NB, 256, 0, stream>>>(compact, rowcnt, coeffs, out);
}

// Round 14
// 104.598 us; speedup vs baseline: 1.1344x; 1.0201x over previous
//
#include <hip/hip_runtime.h>
#include <hip/hip_bf16.h>
#include <math.h>

#define NB 32          // batch
#define TLEN 160000    // samples per batch
#define HOP 600
#define NBINS 256
#define TT 267         // frames: 1 + (160000+1024-1024)/600
#define TTP 268        // padded row stride (16B-aligned rows: 1072 B)
#define NROWS (NB * NBINS)  // 8192
#define LMAX 13

__device__ __forceinline__ unsigned f2key(float f) {
    unsigned b = __float_as_uint(f);
    return (b & 0x80000000u) ? ~b : (b | 0x80000000u);
}
// twiddle LDS padding
__device__ __forceinline__ int P(int i) { return i + (i >> 4); }
// data LDS XOR swizzle: conflict-free for stride-64 sets, stride-4 sets,
// and quad-contiguous b128 access
__device__ __forceinline__ int Q(int i) { return i ^ ((i >> 4) & 0x3C); }
__device__ __forceinline__ float2 cmul(float2 a, float2 w) {
    return make_float2(a.x * w.x - a.y * w.y, a.x * w.y + a.y * w.x);
}
__device__ __forceinline__ float2 cadd(float2 a, float2 b) { return make_float2(a.x + b.x, a.y + b.y); }
__device__ __forceinline__ float2 csub(float2 a, float2 b) { return make_float2(a.x - b.x, a.y - b.y); }

// ---------------------------------------------------------------- init: twiddles + window
__global__ void init_kernel(float2* __restrict__ tw, float* __restrict__ wtab) {
    int j = blockIdx.x * blockDim.x + threadIdx.x;
    if (j < 512) {
        double ang = -2.0 * 3.14159265358979323846 * (double)j / 1024.0;
        tw[j] = make_float2((float)cos(ang), (float)sin(ang));
    }
    if (j < 800) {
        float arg = (6.2831855f * (float)j) / 800.0f;
        wtab[j] = 0.5f - 0.5f * cosf(arg);
    }
}

// ---------------------------------------------------------------- STFT power
// one block per (8 frames, batch) = 4 complex 1024-pt DIF FFTs (each packs two
// real frames). Radix-16/16/4 decomposition: 3 LDS round-trips, 4 barriers.
// Y written as 2x float4 per bin (8 contiguous frame powers).
__global__ __launch_bounds__(256) void stft_power_kernel(
        const float* __restrict__ y, const float2* __restrict__ twg,
        const float* __restrict__ wtab, float* __restrict__ Y) {
    __shared__ float2 zz[4][1024];
    __shared__ float2 twl[544];

    const int g = blockIdx.x;
    const int b = blockIdx.y;
    const int tid = threadIdx.x;
    const int f0 = 8 * g;

    for (int j = tid; j < 512; j += 256) twl[P(j)] = twg[j];

    // ---- stage in: window + pack two real frames per FFT (coalesced float4)
    const float* yb = y + (size_t)b * TLEN;
    #pragma unroll
    for (int a = 0; a < 4; ++a) {
        const int fa = f0 + 2 * a;
        if (fa >= TT) break;
        const bool hasB = (fa + 1 < TT);
        const int base = fa * HOP - 512;        // reflect pad K/2 = 512
        const int i = 4 * tid;
        float2 q4[4];
        if (base >= 0 && hasB) {                // fast path: no reflection possible
            if (i >= 112 && i < 912) {          // centered 800-tap hann
                float4 w4 = *(const float4*)(wtab + (i - 112));
                float4 a0 = *(const float4*)(yb + base + i);
                float4 a1 = *(const float4*)(yb + base + HOP + i);
                q4[0] = make_float2(a0.x * w4.x, a1.x * w4.x);
                q4[1] = make_float2(a0.y * w4.y, a1.y * w4.y);
                q4[2] = make_float2(a0.z * w4.z, a1.z * w4.z);
                q4[3] = make_float2(a0.w * w4.w, a1.w * w4.w);
            } else {
                q4[0] = q4[1] = q4[2] = q4[3] = make_float2(0.f, 0.f);
            }
        } else {                                // fa==0 (left reflect) or fa==266
            #pragma unroll
            for (int m = 0; m < 4; ++m) {
                const int ii = i + m;
                float v0 = 0.f, v1 = 0.f;
                if (ii >= 112 && ii < 912) {
                    float w = wtab[ii - 112];
                    int p0 = base + ii;
                    int q0 = p0 < 0 ? -p0 : p0; // right edge never reflects
                    v0 = yb[q0] * w;
                    if (hasB) v1 = yb[p0 + HOP] * w;
                }
                q4[m] = make_float2(v0, v1);
            }
        }
        float4* dst = (float4*)&zz[a][Q(i)];    // Q preserves quad contiguity
        dst[0] = make_float4(q4[0].x, q4[0].y, q4[1].x, q4[1].y);
        dst[1] = make_float4(q4[2].x, q4[2].y, q4[3].x, q4[3].y);
    }
    __syncthreads();

    // ---- round 1: DIF layers H=512,256,128,64 on {j + 64k} in registers
    {
        const int a = tid >> 6, j = tid & 63;
        float2 x[16];
        #pragma unroll
        for (int k = 0; k < 16; ++k) x[k] = zz[a][Q(j + 64 * k)];
        #pragma unroll
        for (int k = 0; k < 8; ++k) {           // H=512
            float2 s = csub(x[k], x[k + 8]);
            x[k] = cadd(x[k], x[k + 8]);
            x[k + 8] = cmul(s, twl[P(j + 64 * k)]);
        }
        #pragma unroll
        for (int h = 0; h < 16; h += 8)         // H=256
            #pragma unroll
            for (int k = 0; k < 4; ++k) {
                float2 s = csub(x[h + k], x[h + k + 4]);
                x[h + k] = cadd(x[h + k], x[h + k + 4]);
                x[h + k + 4] = cmul(s, twl[P(2 * j + 128 * k)]);
            }
        #pragma unroll
        for (int h = 0; h < 16; h += 4)         // H=128
            #pragma unroll
            for (int k = 0; k < 2; ++k) {
                float2 s = csub(x[h + k], x[h + k + 2]);
                x[h + k] = cadd(x[h + k], x[h + k + 2]);
                x[h + k + 2] = cmul(s, twl[P(4 * j + 256 * k)]);
            }
        {
            const float2 wD = twl[P(8 * j)];    // H=64
            #pragma unroll
            for (int h = 0; h < 16; h += 2) {
                float2 s = csub(x[h], x[h + 1]);
                x[h] = cadd(x[h], x[h + 1]);
                x[h + 1] = cmul(s, wD);
            }
        }
        #pragma unroll
        for (int k = 0; k < 16; ++k) zz[a][Q(j + 64 * k)] = x[k];
    }
    __syncthreads();

    // ---- round 2: DIF layers H=32,16,8,4 on {64g + j2 + 4k} in registers
    {
        const int a = tid >> 6, l = tid & 63;
        const int gg = l >> 2, j2 = l & 3;
        const int b0 = 64 * gg + j2;
        float2 x[16];
        #pragma unroll
        for (int k = 0; k < 16; ++k) x[k] = zz[a][Q(b0 + 4 * k)];
        #pragma unroll
        for (int k = 0; k < 8; ++k) {           // H=32
            float2 s = csub(x[k], x[k + 8]);
            x[k] = cadd(x[k], x[k + 8]);
            x[k + 8] = cmul(s, twl[P(16 * j2 + 64 * k)]);
        }
        #pragma unroll
        for (int h = 0; h < 16; h += 8)         // H=16
            #pragma unroll
            for (int k = 0; k < 4; ++k) {
                float2 s = csub(x[h + k], x[h + k + 4]);
                x[h + k] = cadd(x[h + k], x[h + k + 4]);
                x[h + k + 4] = cmul(s, twl[P(32 * j2 + 128 * k)]);
            }
        #pragma unroll
        for (int h = 0; h < 16; h += 4)         // H=8
            #pragma unroll
            for (int k = 0; k < 2; ++k) {
                float2 s = csub(x[h + k], x[h + k + 2]);
                x[h + k] = cadd(x[h + k], x[h + k + 2]);
                x[h + k + 2] = cmul(s, twl[P(64 * (j2 + 4 * k))]);
            }
        {
            const float2 wD = twl[P(128 * j2)]; // H=4
            #pragma unroll
            for (int h = 0; h < 16; h += 2) {
                float2 s = csub(x[h], x[h + 1]);
                x[h] = cadd(x[h], x[h + 1]);
                x[h + 1] = cmul(s, wD);
            }
        }
        #pragma unroll
        for (int k = 0; k < 16; ++k) zz[a][Q(b0 + 4 * k)] = x[k];
    }
    __syncthreads();

    // ---- round 3: twiddle-free radix-4 on quads (b128 via Q contiguity)
    #pragma unroll
    for (int a = 0; a < 4; ++a) {
        float4* pp = (float4*)&zz[a][Q(4 * tid)];
        float4 r0 = pp[0], r1 = pp[1];
        float2 x0 = make_float2(r0.x, r0.y), x1 = make_float2(r0.z, r0.w);
        float2 x2 = make_float2(r1.x, r1.y), x3 = make_float2(r1.z, r1.w);
        float2 e0 = cadd(x0, x2);
        float2 e1 = cadd(x1, x3);
        float2 d0 = csub(x0, x2);
        float2 d1 = csub(x1, x3);
        float2 d1m = make_float2(d1.y, -d1.x);  // * W^256 = -i
        pp[0] = make_float4(e0.x + e1.x, e0.y + e1.y, e0.x - e1.x, e0.y - e1.y);
        pp[1] = make_float4(d0.x + d1m.x, d0.y + d1m.y, d0.x - d1m.x, d0.y - d1m.y);
    }
    __syncthreads();

    // ---- unpack two real spectra per FFT; Z[k] sits at brev10(k)
    const int k = tid;
    const int nk = (1024 - k) & 1023;
    const int rk = (int)(__brev((unsigned)k) >> 22);
    const int rn = (int)(__brev((unsigned)nk) >> 22);
    float* yrow = Y + ((size_t)b * NBINS + k) * TTP;
    if (g < 33) {                       // all 8 frames valid: 2x float4 stores
        float p[8];
        #pragma unroll
        for (int a = 0; a < 4; ++a) {
            float2 zk = zz[a][Q(rk)], zn = zz[a][Q(rn)];
            float x0r = 0.5f * (zk.x + zn.x), x0i = 0.5f * (zk.y - zn.y);
            float x1r = 0.5f * (zk.y + zn.y), x1i = 0.5f * (zn.x - zk.x);
            p[2 * a]     = x0r * x0r + x0i * x0i;
            p[2 * a + 1] = x1r * x1r + x1i * x1i;
        }
        *(float4*)(yrow + f0)     = make_float4(p[0], p[1], p[2], p[3]);
        *(float4*)(yrow + f0 + 4) = make_float4(p[4], p[5], p[6], p[7]);
    } else {                            // tail block (frames 264..266)
        #pragma unroll
        for (int a = 0; a < 4; ++a) {
            const int fb2 = f0 + 2 * a;
            if (fb2 >= TT) break;
            float2 zk = zz[a][Q(rk)], zn = zz[a][Q(rn)];
            float x0r = 0.5f * (zk.x + zn.x), x0i = 0.5f * (zk.y - zn.y);
            float x1r = 0.5f * (zk.y + zn.y), x1i = 0.5f * (zn.x - zk.x);
            if (fb2 + 1 < TT)
                *(float2*)(yrow + fb2) = make_float2(x0r * x0r + x0i * x0i,
                                                     x1r * x1r + x1i * x1i);
            else
                yrow[fb2] = x0r * x0r + x0i * x0i;
        }
    }
}

// ---------------------------------------------------------------- per-subband
// ONE ROW PER WAVE (2048 blocks x 4 waves). dec flags in ballot registers,
// wave-local compaction, private per-row output region, NO atomics.
__global__ __launch_bounds__(256) void subband_kernel(
        const float* __restrict__ Y, unsigned* __restrict__ compact,
        int* __restrict__ rowcnt) {
    __shared__ float ys[4][272];

    const int tid = threadIdx.x;
    const int lane = tid & 63;
    const int wave = tid >> 6;
    const int row = blockIdx.x * 4 + wave;
    const float* src = Y + (size_t)row * TTP;

    float v[5];
    #pragma unroll
    for (int c = 0; c < 5; ++c) {
        int t = c * 64 + lane;
        v[c] = (t < TT) ? src[t] : 0.0f;
        if (t < TT) ys[wave][t] = v[c];
    }
    __syncthreads();                 // the only barrier

    const float* yy = ys[wave];

    unsigned long long m[5];
    #pragma unroll
    for (int c = 0; c < 5; ++c) {
        int t = c * 64 + lane;
        bool d = (t < TT - 1) && (yy[t + 1] < v[c]);
        m[c] = __ballot(d);
    }

    auto runl = [&](int c, int l) -> int {
        unsigned long long lo = m[c] >> l;
        if (l && c < 4) lo |= m[c + 1] << (64 - l);
        unsigned win = (unsigned)lo & 0xFFFu;
        return (win == 0xFFFu) ? 12 : (__ffs((int)~win) - 1);
    };

    int rl[5];
    int mx = 0;
    #pragma unroll
    for (int c = 0; c < 5; ++c) { rl[c] = runl(c, lane); mx = max(mx, rl[c]); }
    #pragma unroll
    for (int o = 32; o; o >>= 1) mx = max(mx, __shfl_xor(mx, o));
    const int maxrun = mx;           // capped at 12, uniform across wave

    if (maxrun < 2) {                // has_any == false
        if (lane == 0) rowcnt[row] = 0;
        return;
    }
    const int L = maxrun + 1;        // == min(13, true_maxrun+1)

    float sumx = 0.0f;
    #pragma unroll
    for (int j = 0; j < LMAX; ++j) if (j < L) sumx += (float)j;
    const float xm = sumx / (float)L;
    float den = 0.0f;
    #pragma unroll
    for (int j = 0; j < LMAX; ++j) if (j < L) { float xc = (float)j - xm; den += xc * xc; }

    unsigned keys[5];
    unsigned long long vm[5];
    #pragma unroll
    for (int c = 0; c < 5; ++c) {
        const int t = c * 64 + lane;
        bool sel = false;
        unsigned key = 0u;
        if (rl[c] >= L - 1) {        // start_mask (t+L<=T implied by run len)
            float edc[LMAX];
            float s = 0.0f;
            #pragma unroll
            for (int j = LMAX - 1; j >= 0; --j) {
                if (j < L) s += yy[t + j];
                edc[j] = s;
            }
            float db0 = 10.0f * log10f(fmaxf(edc[0], 1e-10f));
            float scl[LMAX];
            float s1 = 0.0f;
            float last = 0.0f;
            #pragma unroll
            for (int j = 0; j < LMAX; ++j) {
                if (j < L) {
                    float db = 10.0f * log10f(fmaxf(edc[j], 1e-10f));
                    float sc = db - db0;
                    scl[j] = sc;
                    s1 += sc;
                    if (j == L - 1) last = sc;
                }
            }
            if (last < -10.0f) {     // selected
                const float ym = s1 / (float)L;
                float num = 0.0f;
                #pragma unroll
                for (int j = 0; j < LMAX; ++j)
                    if (j < L) num += ((float)j - xm) * (scl[j] - ym);
                const float slope = num / den;
                float rt60 = (-60.0f / slope) * 0.0375f;   // * HOP/FS
                sel = true;
                key = f2key(rt60);
            }
        }
        vm[c] = __ballot(sel);       // uniform point
        keys[c] = key;
    }

    unsigned* dst = compact + (size_t)row * TTP;
    const unsigned long long below = (1ull << lane) - 1ull;
    int base = 0;
    #pragma unroll
    for (int c = 0; c < 5; ++c) {
        if (vm[c] & (1ull << lane))
            dst[base + (int)__popcll(vm[c] & below)] = keys[c];
        base += (int)__popcll(vm[c]);
    }
    if (lane == 0) rowcnt[row] = base;
}

// ---------------------------------------------------------------- median
// one block per batch: exact k-th smallest via 3-pass (14+14+4 bit) LDS radix
// select. Conflict-free chunk sums (rotated index), shfl-based parallel rank
// selection (no serial tid0 scans).
__global__ __launch_bounds__(256) void median_kernel(
        const unsigned* __restrict__ compact, const int* __restrict__ rowcnt,
        const float* __restrict__ coeffs, float* __restrict__ out) {
    __shared__ unsigned hist[16384];
    __shared__ unsigned wsum[4];
    __shared__ int sh_sel;
    __shared__ unsigned sh_kkc;
    __shared__ unsigned sh_kk, sh_prefix, sh_pmask;
    __shared__ int sh_n;

    const int b = blockIdx.x;
    const int tid = threadIdx.x;
    const int lane = tid & 63;
    const int wave = tid >> 6;
    const int myrow = b * NBINS + tid;
    const int myc = rowcnt[myrow];
    const unsigned* mykeys = compact + (size_t)myrow * TTP;

    {
        unsigned x = (unsigned)myc;
        #pragma unroll
        for (int o = 1; o < 64; o <<= 1) { unsigned t = __shfl_up(x, o); if (lane >= o) x += t; }
        if (lane == 63) wsum[wave] = x;
        __syncthreads();
        if (tid == 0) {
            int n = (int)(wsum[0] + wsum[1] + wsum[2] + wsum[3]);
            sh_n = n;
            sh_kk = (n > 0) ? (unsigned)((n - 1) / 2) : 0u;
            sh_prefix = 0u; sh_pmask = 0u;
        }
        __syncthreads();
    }
    const int n = sh_n;
    if (n == 0) {
        if (tid == 0) out[b] = 0.5f;     // DEFAULT_RT60 (> 0.01 clamp)
        return;
    }

    const int shifts[3] = {18, 4, 0};
    for (int p = 0; p < 3; ++p) {
        const int shift = shifts[p];
        const bool big = (p < 2);

        if (big) {
            uint4* h4 = (uint4*)hist;
            for (int i = tid; i < 4096; i += 256) h4[i] = make_uint4(0u, 0u, 0u, 0u);
        } else if (tid < 16) hist[tid] = 0u;
        __syncthreads();

        const unsigned pfx = sh_prefix, pm = sh_pmask;
        const unsigned bmask = big ? 16383u : 15u;
        for (int i = 0; i < myc; ++i) {
            unsigned k = mykeys[i];
            if ((k & pm) == pfx) atomicAdd(&hist[(k >> shift) & bmask], 1u);
        }
        __syncthreads();

        const unsigned kk = sh_kk;
        if (big) {
            unsigned s = 0;
            const int base = tid * 64;
            #pragma unroll 8
            for (int ii = 0; ii < 64; ++ii) s += hist[base + ((ii + tid) & 63)];
            unsigned x = s;
            #pragma unroll
            for (int o = 1; o < 64; o <<= 1) { unsigned t = __shfl_up(x, o); if (lane >= o) x += t; }
            if (lane == 63) wsum[wave] = x;
            __syncthreads();
            unsigned woff = 0;
            for (int w = 0; w < wave; ++w) woff += wsum[w];
            const unsigned incl = x + woff, excl = incl - s;
            if (kk >= excl && kk < incl) { sh_sel = tid; sh_kkc = kk - excl; }
            __syncthreads();
            const int sel = sh_sel;
            const unsigned kkc = sh_kkc;
            if (wave == 0) {
                unsigned h = hist[sel * 64 + lane];
                unsigned xx = h;
                #pragma unroll
                for (int o = 1; o < 64; o <<= 1) { unsigned t = __shfl_up(xx, o); if (lane >= o) xx += t; }
                unsigned ex = xx - h;
                if (kkc >= ex && kkc < xx) {
                    sh_prefix = pfx | ((unsigned)(sel * 64 + lane) << shift);
                    sh_pmask  = pm | (16383u << shift);
                    sh_kk = kkc - ex;
                }
            }
            __syncthreads();
        } else {
            if (wave == 0) {
                unsigned h = (lane < 16) ? hist[lane] : 0u;
                unsigned xx = h;
                #pragma unroll
                for (int o = 1; o < 64; o <<= 1) { unsigned t = __shfl_up(xx, o); if (lane >= o) xx += t; }
                unsigned ex = xx - h;
                if (lane < 16 && kk >= ex && kk < xx)
                    sh_prefix = pfx | (unsigned)lane;   // shift == 0
            }
            __syncthreads();
        }
    }

    if (tid == 0) {
        unsigned kx = sh_prefix;
        unsigned fb = (kx & 0x80000000u) ? (kx & 0x7FFFFFFFu) : ~kx;
        float med = __uint_as_float(fb);
        out[b] = fmaxf(coeffs[0] + coeffs[1] * med, 0.01f);
    }
}

// ----------------------------------------------------------------
extern "C" void kernel_launch(void* const* d_in, const int* in_sizes, int n_in,
                              void* d_out, int out_size, void* d_ws, size_t ws_size,
                              hipStream_t stream) {
    const float* y = (const float*)d_in[0];
    const float* coeffs = (const float*)d_in[1];
    float* out = (float*)d_out;

    // ws layout:
    //   [0]        Y       : NROWS*TTP floats (stride-268 rows)
    //   [YB]       compact : NROWS*TTP uints (per-row private regions)
    //   [2*YB]     rowcnt  : NROWS ints (fully overwritten per call)
    //   [..]       tw      : 512 float2 ; wtab : 800 floats
    const size_t YB = (size_t)NROWS * TTP * sizeof(float);
    char* base = (char*)d_ws;
    float* Y = (float*)base;
    unsigned* compact = (unsigned*)(base + YB);
    int* rowcnt = (int*)(base + 2 * YB);
    float2* tw = (float2*)(base + 2 * YB + (size_t)NROWS * sizeof(int));
    float* wtab = (float*)((char*)tw + 512 * sizeof(float2));

    init_kernel<<<4, 256, 0, stream>>>(tw, wtab);
    stft_power_kernel<<<dim3((TT + 7) / 8, NB), 256, 0, stream>>>(y, tw, wtab, Y);
    subband_kernel<<<NROWS / 4, 256, 0, stream>>>(Y, compact, rowcnt);
    median_kernel<<<NB, 256, 0, stream>>>(compact, rowcnt, coeffs, out);
}

// Round 15
// 97.669 us; speedup vs baseline: 1.2149x; 1.0709x over previous
//
#include <hip/hip_runtime.h>
#include <hip/hip_bf16.h>
#include <math.h>

#define NB 32          // batch
#define TLEN 160000    // samples per batch
#define HOP 600
#define NBINS 256
#define TT 267         // frames: 1 + (160000+1024-1024)/600
#define TTP 268        // padded row stride (16B-aligned rows: 1072 B)
#define NROWS (NB * NBINS)  // 8192
#define LMAX 13

__device__ __forceinline__ unsigned f2key(float f) {
    unsigned b = __float_as_uint(f);
    return (b & 0x80000000u) ? ~b : (b | 0x80000000u);
}
// twiddle LDS padding
__device__ __forceinline__ int P(int i) { return i + (i >> 4); }
// data LDS XOR swizzle: conflict-free for stride-64 sets, stride-4 sets,
// and quad-contiguous b128 access
__device__ __forceinline__ int Q(int i) { return i ^ ((i >> 4) & 0x3C); }
__device__ __forceinline__ float2 cmul(float2 a, float2 w) {
    return make_float2(a.x * w.x - a.y * w.y, a.x * w.y + a.y * w.x);
}
__device__ __forceinline__ float2 cadd(float2 a, float2 b) { return make_float2(a.x + b.x, a.y + b.y); }
__device__ __forceinline__ float2 csub(float2 a, float2 b) { return make_float2(a.x - b.x, a.y - b.y); }

// ---------------------------------------------------------------- init: twiddles + window
__global__ void init_kernel(float2* __restrict__ tw, float* __restrict__ wtab) {
    int j = blockIdx.x * blockDim.x + threadIdx.x;
    if (j < 512) {
        double ang = -2.0 * 3.14159265358979323846 * (double)j / 1024.0;
        tw[j] = make_float2((float)cos(ang), (float)sin(ang));
    }
    if (j < 800) {
        float arg = (6.2831855f * (float)j) / 800.0f;
        wtab[j] = 0.5f - 0.5f * cosf(arg);
    }
}

// ---------------------------------------------------------------- STFT power
// one block per (8 frames, batch) = 4 complex 1024-pt DIF FFTs (each packs two
// real frames). Radix-16/16/4 decomposition: 3 LDS round-trips, 4 barriers.
// Y written as 2x float4 per bin (8 contiguous frame powers).
// EXACT R14 version (known good).
__global__ __launch_bounds__(256) void stft_power_kernel(
        const float* __restrict__ y, const float2* __restrict__ twg,
        const float* __restrict__ wtab, float* __restrict__ Y) {
    __shared__ float2 zz[4][1024];
    __shared__ float2 twl[544];

    const int g = blockIdx.x;
    const int b = blockIdx.y;
    const int tid = threadIdx.x;
    const int f0 = 8 * g;

    for (int j = tid; j < 512; j += 256) twl[P(j)] = twg[j];

    // ---- stage in: window + pack two real frames per FFT (coalesced float4)
    const float* yb = y + (size_t)b * TLEN;
    #pragma unroll
    for (int a = 0; a < 4; ++a) {
        const int fa = f0 + 2 * a;
        if (fa >= TT) break;
        const bool hasB = (fa + 1 < TT);
        const int base = fa * HOP - 512;        // reflect pad K/2 = 512
        const int i = 4 * tid;
        float2 q4[4];
        if (base >= 0 && hasB) {                // fast path: no reflection possible
            if (i >= 112 && i < 912) {          // centered 800-tap hann
                float4 w4 = *(const float4*)(wtab + (i - 112));
                float4 a0 = *(const float4*)(yb + base + i);
                float4 a1 = *(const float4*)(yb + base + HOP + i);
                q4[0] = make_float2(a0.x * w4.x, a1.x * w4.x);
                q4[1] = make_float2(a0.y * w4.y, a1.y * w4.y);
                q4[2] = make_float2(a0.z * w4.z, a1.z * w4.z);
                q4[3] = make_float2(a0.w * w4.w, a1.w * w4.w);
            } else {
                q4[0] = q4[1] = q4[2] = q4[3] = make_float2(0.f, 0.f);
            }
        } else {                                // fa==0 (left reflect) or fa==266
            #pragma unroll
            for (int m = 0; m < 4; ++m) {
                const int ii = i + m;
                float v0 = 0.f, v1 = 0.f;
                if (ii >= 112 && ii < 912) {
                    float w = wtab[ii - 112];
                    int p0 = base + ii;
                    int q0 = p0 < 0 ? -p0 : p0; // right edge never reflects
                    v0 = yb[q0] * w;
                    if (hasB) v1 = yb[p0 + HOP] * w;
                }
                q4[m] = make_float2(v0, v1);
            }
        }
        float4* dst = (float4*)&zz[a][Q(i)];    // Q preserves quad contiguity
        dst[0] = make_float4(q4[0].x, q4[0].y, q4[1].x, q4[1].y);
        dst[1] = make_float4(q4[2].x, q4[2].y, q4[3].x, q4[3].y);
    }
    __syncthreads();

    // ---- round 1: DIF layers H=512,256,128,64 on {j + 64k} in registers
    {
        const int a = tid >> 6, j = tid & 63;
        float2 x[16];
        #pragma unroll
        for (int k = 0; k < 16; ++k) x[k] = zz[a][Q(j + 64 * k)];
        #pragma unroll
        for (int k = 0; k < 8; ++k) {           // H=512
            float2 s = csub(x[k], x[k + 8]);
            x[k] = cadd(x[k], x[k + 8]);
            x[k + 8] = cmul(s, twl[P(j + 64 * k)]);
        }
        #pragma unroll
        for (int h = 0; h < 16; h += 8)         // H=256
            #pragma unroll
            for (int k = 0; k < 4; ++k) {
                float2 s = csub(x[h + k], x[h + k + 4]);
                x[h + k] = cadd(x[h + k], x[h + k + 4]);
                x[h + k + 4] = cmul(s, twl[P(2 * j + 128 * k)]);
            }
        #pragma unroll
        for (int h = 0; h < 16; h += 4)         // H=128
            #pragma unroll
            for (int k = 0; k < 2; ++k) {
                float2 s = csub(x[h + k], x[h + k + 2]);
                x[h + k] = cadd(x[h + k], x[h + k + 2]);
                x[h + k + 2] = cmul(s, twl[P(4 * j + 256 * k)]);
            }
        {
            const float2 wD = twl[P(8 * j)];    // H=64
            #pragma unroll
            for (int h = 0; h < 16; h += 2) {
                float2 s = csub(x[h], x[h + 1]);
                x[h] = cadd(x[h], x[h + 1]);
                x[h + 1] = cmul(s, wD);
            }
        }
        #pragma unroll
        for (int k = 0; k < 16; ++k) zz[a][Q(j + 64 * k)] = x[k];
    }
    __syncthreads();

    // ---- round 2: DIF layers H=32,16,8,4 on {64g + j2 + 4k} in registers
    {
        const int a = tid >> 6, l = tid & 63;
        const int gg = l >> 2, j2 = l & 3;
        const int b0 = 64 * gg + j2;
        float2 x[16];
        #pragma unroll
        for (int k = 0; k < 16; ++k) x[k] = zz[a][Q(b0 + 4 * k)];
        #pragma unroll
        for (int k = 0; k < 8; ++k) {           // H=32
            float2 s = csub(x[k], x[k + 8]);
            x[k] = cadd(x[k], x[k + 8]);
            x[k + 8] = cmul(s, twl[P(16 * j2 + 64 * k)]);
        }
        #pragma unroll
        for (int h = 0; h < 16; h += 8)         // H=16
            #pragma unroll
            for (int k = 0; k < 4; ++k) {
                float2 s = csub(x[h + k], x[h + k + 4]);
                x[h + k] = cadd(x[h + k], x[h + k + 4]);
                x[h + k + 4] = cmul(s, twl[P(32 * j2 + 128 * k)]);
            }
        #pragma unroll
        for (int h = 0; h < 16; h += 4)         // H=8
            #pragma unroll
            for (int k = 0; k < 2; ++k) {
                float2 s = csub(x[h + k], x[h + k + 2]);
                x[h + k] = cadd(x[h + k], x[h + k + 2]);
                x[h + k + 2] = cmul(s, twl[P(64 * (j2 + 4 * k))]);
            }
        {
            const float2 wD = twl[P(128 * j2)]; // H=4
            #pragma unroll
            for (int h = 0; h < 16; h += 2) {
                float2 s = csub(x[h], x[h + 1]);
                x[h] = cadd(x[h], x[h + 1]);
                x[h + 1] = cmul(s, wD);
            }
        }
        #pragma unroll
        for (int k = 0; k < 16; ++k) zz[a][Q(b0 + 4 * k)] = x[k];
    }
    __syncthreads();

    // ---- round 3: twiddle-free radix-4 on quads (b128 via Q contiguity)
    #pragma unroll
    for (int a = 0; a < 4; ++a) {
        float4* pp = (float4*)&zz[a][Q(4 * tid)];
        float4 r0 = pp[0], r1 = pp[1];
        float2 x0 = make_float2(r0.x, r0.y), x1 = make_float2(r0.z, r0.w);
        float2 x2 = make_float2(r1.x, r1.y), x3 = make_float2(r1.z, r1.w);
        float2 e0 = cadd(x0, x2);
        float2 e1 = cadd(x1, x3);
        float2 d0 = csub(x0, x2);
        float2 d1 = csub(x1, x3);
        float2 d1m = make_float2(d1.y, -d1.x);  // * W^256 = -i
        pp[0] = make_float4(e0.x + e1.x, e0.y + e1.y, e0.x - e1.x, e0.y - e1.y);
        pp[1] = make_float4(d0.x + d1m.x, d0.y + d1m.y, d0.x - d1m.x, d0.y - d1m.y);
    }
    __syncthreads();

    // ---- unpack two real spectra per FFT; Z[k] sits at brev10(k)
    const int k = tid;
    const int nk = (1024 - k) & 1023;
    const int rk = (int)(__brev((unsigned)k) >> 22);
    const int rn = (int)(__brev((unsigned)nk) >> 22);
    float* yrow = Y + ((size_t)b * NBINS + k) * TTP;
    if (g < 33) {                       // all 8 frames valid: 2x float4 stores
        float p[8];
        #pragma unroll
        for (int a = 0; a < 4; ++a) {
            float2 zk = zz[a][Q(rk)], zn = zz[a][Q(rn)];
            float x0r = 0.5f * (zk.x + zn.x), x0i = 0.5f * (zk.y - zn.y);
            float x1r = 0.5f * (zk.y + zn.y), x1i = 0.5f * (zn.x - zk.x);
            p[2 * a]     = x0r * x0r + x0i * x0i;
            p[2 * a + 1] = x1r * x1r + x1i * x1i;
        }
        *(float4*)(yrow + f0)     = make_float4(p[0], p[1], p[2], p[3]);
        *(float4*)(yrow + f0 + 4) = make_float4(p[4], p[5], p[6], p[7]);
    } else {                            // tail block (frames 264..266)
        #pragma unroll
        for (int a = 0; a < 4; ++a) {
            const int fb2 = f0 + 2 * a;
            if (fb2 >= TT) break;
            float2 zk = zz[a][Q(rk)], zn = zz[a][Q(rn)];
            float x0r = 0.5f * (zk.x + zn.x), x0i = 0.5f * (zk.y - zn.y);
            float x1r = 0.5f * (zk.y + zn.y), x1i = 0.5f * (zn.x - zk.x);
            if (fb2 + 1 < TT)
                *(float2*)(yrow + fb2) = make_float2(x0r * x0r + x0i * x0i,
                                                     x1r * x1r + x1i * x1i);
            else
                yrow[fb2] = x0r * x0r + x0i * x0i;
        }
    }
}

// ---------------------------------------------------------------- per-subband
// ONE ROW PER WAVE (2048 blocks x 4 waves). dec flags in ballot registers,
// wave-local compaction, private per-row output region, NO atomics.
// EXACT R14 version (known good).
__global__ __launch_bounds__(256) void subband_kernel(
        const float* __restrict__ Y, unsigned* __restrict__ compact,
        int* __restrict__ rowcnt) {
    __shared__ float ys[4][272];

    const int tid = threadIdx.x;
    const int lane = tid & 63;
    const int wave = tid >> 6;
    const int row = blockIdx.x * 4 + wave;
    const float* src = Y + (size_t)row * TTP;

    float v[5];
    #pragma unroll
    for (int c = 0; c < 5; ++c) {
        int t = c * 64 + lane;
        v[c] = (t < TT) ? src[t] : 0.0f;
        if (t < TT) ys[wave][t] = v[c];
    }
    __syncthreads();                 // the only barrier

    const float* yy = ys[wave];

    unsigned long long m[5];
    #pragma unroll
    for (int c = 0; c < 5; ++c) {
        int t = c * 64 + lane;
        bool d = (t < TT - 1) && (yy[t + 1] < v[c]);
        m[c] = __ballot(d);
    }

    auto runl = [&](int c, int l) -> int {
        unsigned long long lo = m[c] >> l;
        if (l && c < 4) lo |= m[c + 1] << (64 - l);
        unsigned win = (unsigned)lo & 0xFFFu;
        return (win == 0xFFFu) ? 12 : (__ffs((int)~win) - 1);
    };

    int rl[5];
    int mx = 0;
    #pragma unroll
    for (int c = 0; c < 5; ++c) { rl[c] = runl(c, lane); mx = max(mx, rl[c]); }
    #pragma unroll
    for (int o = 32; o; o >>= 1) mx = max(mx, __shfl_xor(mx, o));
    const int maxrun = mx;           // capped at 12, uniform across wave

    if (maxrun < 2) {                // has_any == false
        if (lane == 0) rowcnt[row] = 0;
        return;
    }
    const int L = maxrun + 1;        // == min(13, true_maxrun+1)

    float sumx = 0.0f;
    #pragma unroll
    for (int j = 0; j < LMAX; ++j) if (j < L) sumx += (float)j;
    const float xm = sumx / (float)L;
    float den = 0.0f;
    #pragma unroll
    for (int j = 0; j < LMAX; ++j) if (j < L) { float xc = (float)j - xm; den += xc * xc; }

    unsigned keys[5];
    unsigned long long vm[5];
    #pragma unroll
    for (int c = 0; c < 5; ++c) {
        const int t = c * 64 + lane;
        bool sel = false;
        unsigned key = 0u;
        if (rl[c] >= L - 1) {        // start_mask (t+L<=T implied by run len)
            float edc[LMAX];
            float s = 0.0f;
            #pragma unroll
            for (int j = LMAX - 1; j >= 0; --j) {
                if (j < L) s += yy[t + j];
                edc[j] = s;
            }
            float db0 = 10.0f * log10f(fmaxf(edc[0], 1e-10f));
            float scl[LMAX];
            float s1 = 0.0f;
            float last = 0.0f;
            #pragma unroll
            for (int j = 0; j < LMAX; ++j) {
                if (j < L) {
                    float db = 10.0f * log10f(fmaxf(edc[j], 1e-10f));
                    float sc = db - db0;
                    scl[j] = sc;
                    s1 += sc;
                    if (j == L - 1) last = sc;
                }
            }
            if (last < -10.0f) {     // selected
                const float ym = s1 / (float)L;
                float num = 0.0f;
                #pragma unroll
                for (int j = 0; j < LMAX; ++j)
                    if (j < L) num += ((float)j - xm) * (scl[j] - ym);
                const float slope = num / den;
                float rt60 = (-60.0f / slope) * 0.0375f;   // * HOP/FS
                sel = true;
                key = f2key(rt60);
            }
        }
        vm[c] = __ballot(sel);       // uniform point
        keys[c] = key;
    }

    unsigned* dst = compact + (size_t)row * TTP;
    const unsigned long long below = (1ull << lane) - 1ull;
    int base = 0;
    #pragma unroll
    for (int c = 0; c < 5; ++c) {
        if (vm[c] & (1ull << lane))
            dst[base + (int)__popcll(vm[c] & below)] = keys[c];
        base += (int)__popcll(vm[c]);
    }
    if (lane == 0) rowcnt[row] = base;
}

// ---------------------------------------------------------------- median
// one block per batch: exact k-th smallest via 3-pass (12+12+8 bit) radix
// select over DENSELY LDS-STAGED keys (uniform stride-256 loops, no per-row
// imbalance). Fallback to global reads if n > 16384 (exactness preserved).
__global__ __launch_bounds__(256) void median_kernel(
        const unsigned* __restrict__ compact, const int* __restrict__ rowcnt,
        const float* __restrict__ coeffs, float* __restrict__ out) {
    __shared__ unsigned lkeys[16384];
    __shared__ unsigned hist[4096];
    __shared__ unsigned wsum[4];
    __shared__ unsigned sh_kk, sh_kkc, sh_prefix, sh_pmask;
    __shared__ int sh_sel, sh_n;

    const int b = blockIdx.x;
    const int tid = threadIdx.x;
    const int lane = tid & 63;
    const int wave = tid >> 6;
    const int myrow = b * NBINS + tid;
    const int myc = rowcnt[myrow];
    const unsigned* mykeys = compact + (size_t)myrow * TTP;

    // prefix scan of row counts -> n and my dense offset
    unsigned x = (unsigned)myc;
    #pragma unroll
    for (int o = 1; o < 64; o <<= 1) { unsigned t = __shfl_up(x, o); if (lane >= o) x += t; }
    if (lane == 63) wsum[wave] = x;
    __syncthreads();
    unsigned woff = 0;
    for (int w = 0; w < wave; ++w) woff += wsum[w];
    const int myoff = (int)(woff + x) - myc;    // exclusive offset
    if (tid == 0) {
        int n = (int)(wsum[0] + wsum[1] + wsum[2] + wsum[3]);
        sh_n = n;
        sh_kk = (n > 0) ? (unsigned)((n - 1) / 2) : 0u;
        sh_prefix = 0u; sh_pmask = 0u;
    }
    __syncthreads();
    const int n = sh_n;
    if (n == 0) {
        if (tid == 0) out[b] = 0.5f;    // DEFAULT_RT60 (> 0.01 clamp)
        return;
    }

    const bool inlds = (n <= 16384);
    if (inlds)
        for (int i = 0; i < myc; ++i) lkeys[myoff + i] = mykeys[i];
    __syncthreads();

    const int shifts[3] = {20, 8, 0};
    for (int p = 0; p < 3; ++p) {
        const int shift = shifts[p];
        const bool big = (p < 2);
        const unsigned bmask = big ? 4095u : 255u;

        {   // zero hist (4096 bins, uint4)
            uint4* h4 = (uint4*)hist;
            for (int i = tid; i < 1024; i += 256) h4[i] = make_uint4(0u, 0u, 0u, 0u);
        }
        __syncthreads();

        const unsigned pfx = sh_prefix, pm = sh_pmask;
        if (inlds) {
            for (int i = tid; i < n; i += 256) {
                unsigned k = lkeys[i];
                if ((k & pm) == pfx) atomicAdd(&hist[(k >> shift) & bmask], 1u);
            }
        } else {
            for (int i = 0; i < myc; ++i) {
                unsigned k = mykeys[i];
                if ((k & pm) == pfx) atomicAdd(&hist[(k >> shift) & bmask], 1u);
            }
        }
        __syncthreads();

        const unsigned kk = sh_kk;
        // per-thread chunk sum (16 bins for big passes, 1 bin for last)
        unsigned s = 0;
        if (big) {
            const int base2 = tid * 16;
            #pragma unroll
            for (int ii = 0; ii < 16; ++ii) s += hist[base2 + ((ii + tid) & 15)];
        } else {
            s = hist[tid];
        }
        // block inclusive scan of chunk sums
        unsigned xs = s;
        #pragma unroll
        for (int o = 1; o < 64; o <<= 1) { unsigned t = __shfl_up(xs, o); if (lane >= o) xs += t; }
        if (lane == 63) wsum[wave] = xs;
        __syncthreads();
        unsigned wo = 0;
        for (int w = 0; w < wave; ++w) wo += wsum[w];
        const unsigned incl = xs + wo, excl = incl - s;
        if (kk >= excl && kk < incl) {
            if (big) { sh_sel = tid; sh_kkc = kk - excl; }
            else     { sh_prefix = pfx | (unsigned)tid; }   // bin == tid, done
        }
        __syncthreads();

        if (big) {
            const int sel = sh_sel;
            const unsigned kkc = sh_kkc;
            if (wave == 0) {            // rank-select within the 16-bin chunk
                unsigned h = (lane < 16) ? hist[sel * 16 + lane] : 0u;
                unsigned xx = h;
                #pragma unroll
                for (int o = 1; o < 64; o <<= 1) { unsigned t = __shfl_up(xx, o); if (lane >= o) xx += t; }
                unsigned ex = xx - h;
                if (lane < 16 && kkc >= ex && kkc < xx) {
                    sh_prefix = pfx | ((unsigned)(sel * 16 + lane) << shift);
                    sh_pmask  = pm | (bmask << shift);
                    sh_kk = kkc - ex;
                }
            }
            __syncthreads();
        }
    }

    if (tid == 0) {
        unsigned kx = sh_prefix;
        unsigned fb = (kx & 0x80000000u) ? (kx & 0x7FFFFFFFu) : ~kx;
        float med = __uint_as_float(fb);
        out[b] = fmaxf(coeffs[0] + coeffs[1] * med, 0.01f);
    }
}

// ----------------------------------------------------------------
extern "C" void kernel_launch(void* const* d_in, const int* in_sizes, int n_in,
                              void* d_out, int out_size, void* d_ws, size_t ws_size,
                              hipStream_t stream) {
    const float* y = (const float*)d_in[0];
    const float* coeffs = (const float*)d_in[1];
    float* out = (float*)d_out;

    // ws layout:
    //   [0]        Y       : NROWS*TTP floats (stride-268 rows)
    //   [YB]       compact : NROWS*TTP uints (per-row private regions)
    //   [2*YB]     rowcnt  : NROWS ints (fully overwritten per call)
    //   [..]       tw      : 512 float2 ; wtab : 800 floats
    const size_t YB = (size_t)NROWS * TTP * sizeof(float);
    char* base = (char*)d_ws;
    float* Y = (float*)base;
    unsigned* compact = (unsigned*)(base + YB);
    int* rowcnt = (int*)(base + 2 * YB);
    float2* tw = (float2*)(base + 2 * YB + (size_t)NROWS * sizeof(int));
    float* wtab = (float*)((char*)tw + 512 * sizeof(float2));

    init_kernel<<<4, 256, 0, stream>>>(tw, wtab);
    stft_power_kernel<<<dim3((TT + 7) / 8, NB), 256, 0, stream>>>(y, tw, wtab, Y);
    subband_kernel<<<NROWS / 4, 256, 0, stream>>>(Y, compact, rowcnt);
    median_kernel<<<NB, 256, 0, stream>>>(compact, rowcnt, coeffs, out);
}